// Round 2
// baseline (1204.044 us; speedup 1.0000x reference)
//
#include <hip/hip_runtime.h>

typedef __attribute__((ext_vector_type(8))) __bf16 bf16x8;
typedef __attribute__((ext_vector_type(4))) float floatx4;

__device__ __forceinline__ float bf2f(unsigned short u) {
    union { unsigned int i; float f; } v; v.i = ((unsigned int)u) << 16; return v.f;
}
__device__ __forceinline__ unsigned short f2bf(float f) {
    union { float f; unsigned int i; } v; v.f = f;
    unsigned int u = v.i;
    return (unsigned short)((u + 0x7fffu + ((u >> 16) & 1u)) >> 16);
}

// async global->LDS, 16B per lane. LDS dest = wave-uniform base + lane*16.
__device__ __forceinline__ void async16(const void* g, void* l) {
    __builtin_amdgcn_global_load_lds(
        (__attribute__((address_space(1))) void*)(g),
        (__attribute__((address_space(3))) void*)(l), 16, 0, 0);
}

// ---------------------------------------------------------------------------
// dtype detection: look at even-index u16s of Wq (scale-0.02 values).
// bf16 input: those are bf16 values, exponent field in ~[100,126] nearly always.
// fp32 input: those are float mantissa low-halves, exponent field ~uniform.
// flag = 1 -> inputs are bf16; flag = 0 -> inputs are fp32.
// ---------------------------------------------------------------------------
__global__ void detect_dtype(const unsigned short* __restrict__ w, int* __restrict__ flag)
{
    int tid = threadIdx.x;  // 64 threads
    int cnt = 0;
    for (int i = tid; i < 256; i += 64) {
        unsigned short s = w[2 * i];
        int e = (s >> 7) & 0xFF;
        if (e >= 100 && e <= 126) cnt++;
    }
#pragma unroll
    for (int off = 32; off > 0; off >>= 1) cnt += __shfl_xor(cnt, off);
    if (tid == 0) *flag = (cnt >= 128) ? 1 : 0;
}

// ---------------------------------------------------------------------------
// convert any input array to canonical bf16 (copy if already bf16)
// 4 elements per thread. n must be a multiple of 4.
// ---------------------------------------------------------------------------
__global__ __launch_bounds__(256)
void convert_bf16(const void* __restrict__ in, unsigned short* __restrict__ out,
                  int n, const int* __restrict__ flag)
{
    int i = (blockIdx.x * 256 + threadIdx.x) * 4;
    if (i >= n) return;
    if (*flag) {
        *(uint2*)(out + i) = *(const uint2*)((const unsigned short*)in + i);
    } else {
        float4 f = *(const float4*)((const float*)in + i);
        union { uint2 u; unsigned short s[4]; } W;
        W.s[0] = f2bf(f.x); W.s[1] = f2bf(f.y); W.s[2] = f2bf(f.z); W.s[3] = f2bf(f.w);
        *(uint2*)(out + i) = W.u;
    }
}

// ---------------------------------------------------------------------------
// xr[b*512+n][f*16+t] = x[t][b][n][f]  (bf16 out; x read per detected dtype)
// block = one (b,n), 256 threads, LDS transpose with stride-24 padding.
// ---------------------------------------------------------------------------
__global__ __launch_bounds__(256)
void build_xr(const void* __restrict__ xv, unsigned short* __restrict__ xr,
              const int* __restrict__ flag)
{
    __shared__ __align__(16) unsigned short tile[128 * 24];
    const int bn = blockIdx.x;          // b*512 + n
    const int b = bn >> 9, n = bn & 511;
    const int tid = threadIdx.x;
    const int t = tid >> 4, l16 = tid & 15;

    const long off = (long)(t * 32 + b) * 65536 + n * 128 + l16 * 8;
    union { uint4 u; unsigned short s[8]; } U;
    if (*flag) {
        U.u = *(const uint4*)((const unsigned short*)xv + off);
    } else {
        const float* xf = (const float*)xv + off;
        float4 f0 = *(const float4*)xf;
        float4 f1 = *(const float4*)(xf + 4);
        U.s[0] = f2bf(f0.x); U.s[1] = f2bf(f0.y); U.s[2] = f2bf(f0.z); U.s[3] = f2bf(f0.w);
        U.s[4] = f2bf(f1.x); U.s[5] = f2bf(f1.y); U.s[6] = f2bf(f1.z); U.s[7] = f2bf(f1.w);
    }
#pragma unroll
    for (int j = 0; j < 8; j++) tile[(l16 * 8 + j) * 24 + t] = U.s[j];
    __syncthreads();

    const int f = tid >> 1, t0 = (tid & 1) * 8;
    uint4 o = *(const uint4*)&tile[f * 24 + t0];
    *(uint4*)(xr + (long)bn * 2048 + tid * 8) = o;
}

// ---------------------------------------------------------------------------
// NT GEMM: C = A (MxK row-major) * B^T (B NxK row-major), fp32 accum.
// 128x128 tile, BK=32, 4 waves of 64x64 (4x4 MFMA 16x16x32 bf16).
// MODE 0: bf16 store, optional bias[col]. MODE 1: fp32 store, no bias.
// MODE 3: bf16 store, optional bias[row]. Batched via blockIdx.z.
// ---------------------------------------------------------------------------
template <int MODE, bool BIAS>
__global__ __launch_bounds__(256)
void gemm_nt(const unsigned short* __restrict__ Ag,
             const unsigned short* __restrict__ Bg,
             void* __restrict__ Cg,
             const unsigned short* __restrict__ bias,
             int K, long sA, long sB, long sC, int ldc)
{
    __shared__ __align__(16) unsigned short lsA[128 * 32];
    __shared__ __align__(16) unsigned short lsB[128 * 32];

    const int tid = threadIdx.x;
    const int z = blockIdx.z;
    const unsigned short* A = Ag + (long)z * sA + (long)blockIdx.y * 128 * K;
    const unsigned short* B = Bg + (long)z * sB + (long)blockIdx.x * 128 * K;

    const int wave = tid >> 6, lane = tid & 63;
    const int wm = (wave >> 1) * 64, wn = (wave & 1) * 64;
    const int r = lane & 15, quad = lane >> 4;

    floatx4 acc[4][4];
#pragma unroll
    for (int i = 0; i < 4; i++)
#pragma unroll
        for (int j = 0; j < 4; j++) acc[i][j] = floatx4{0.f, 0.f, 0.f, 0.f};

    const int srow = tid >> 2;            // row 0..63
    const int scol = (tid & 3) * 8;       // k-offset in elements
    const long a0 = (long)srow * K + scol;
    const long a1 = (long)(srow + 64) * K + scol;

    for (int k0 = 0; k0 < K; k0 += 32) {
        async16(A + k0 + a0, (char*)lsA + tid * 16);
        async16(A + k0 + a1, (char*)lsA + 4096 + tid * 16);
        async16(B + k0 + a0, (char*)lsB + tid * 16);
        async16(B + k0 + a1, (char*)lsB + 4096 + tid * 16);
        __syncthreads();

        const bf16x8* pA = (const bf16x8*)lsA;
        const bf16x8* pB = (const bf16x8*)lsB;
        bf16x8 af[4], bb[4];
#pragma unroll
        for (int i = 0; i < 4; i++) af[i] = pA[(wm + i * 16 + r) * 4 + quad];
#pragma unroll
        for (int j = 0; j < 4; j++) bb[j] = pB[(wn + j * 16 + r) * 4 + quad];
#pragma unroll
        for (int i = 0; i < 4; i++)
#pragma unroll
            for (int j = 0; j < 4; j++)
                acc[i][j] = __builtin_amdgcn_mfma_f32_16x16x32_bf16(af[i], bb[j], acc[i][j], 0, 0, 0);
        __syncthreads();
    }

    // C/D layout (16x16x32 bf16, HW-verified): col = lane&15, row = quad*4 + reg
    const int mb = blockIdx.y * 128 + wm + quad * 4;
    const int nb = blockIdx.x * 128 + wn + r;

    if (MODE == 1) {
        float* C = (float*)Cg + (long)z * sC;
#pragma unroll
        for (int i = 0; i < 4; i++)
#pragma unroll
            for (int j = 0; j < 4; j++)
#pragma unroll
                for (int g = 0; g < 4; g++)
                    C[(long)(mb + i * 16 + g) * ldc + (nb + j * 16)] = acc[i][j][g];
    } else if (MODE == 0) {
        unsigned short* C = (unsigned short*)Cg + (long)z * sC;
#pragma unroll
        for (int j = 0; j < 4; j++) {
            const int n = nb + j * 16;
            const float bj = BIAS ? bf2f(bias[n]) : 0.0f;
#pragma unroll
            for (int i = 0; i < 4; i++)
#pragma unroll
                for (int g = 0; g < 4; g++)
                    C[(long)(mb + i * 16 + g) * ldc + n] = f2bf(acc[i][j][g] + bj);
        }
    } else { // MODE 3: bias per row m
        unsigned short* C = (unsigned short*)Cg + (long)z * sC;
#pragma unroll
        for (int i = 0; i < 4; i++)
#pragma unroll
            for (int g = 0; g < 4; g++) {
                const int m = mb + i * 16 + g;
                const float bm = BIAS ? bf2f(bias[m]) : 0.0f;
#pragma unroll
                for (int j = 0; j < 4; j++)
                    C[(long)m * ldc + (nb + j * 16)] = f2bf(acc[i][j][g] + bm);
            }
    }
}

// ---------------------------------------------------------------------------
// Row softmax. Writes bf16 P into ws (Pb, PV-GEMM input) AND the attention
// output chunk of d_out in the detected output dtype.
// One block per row (32*512), 256 threads, 2 cols/thread.
// ---------------------------------------------------------------------------
__global__ __launch_bounds__(256)
void softmax_rows(const float* __restrict__ S, unsigned short* __restrict__ Pb,
                  void* __restrict__ dout, const int* __restrict__ flag)
{
    const long row = blockIdx.x;
    const int tid = threadIdx.x;
    const float scale = 0.02209708691207961f; // 1/sqrt(2048)
    float2 v = ((const float2*)(S + row * 512))[tid];
    float a = v.x * scale, b = v.y * scale;

    __shared__ float redm[4], reds[4];
    float m = fmaxf(a, b);
#pragma unroll
    for (int off = 32; off > 0; off >>= 1) m = fmaxf(m, __shfl_xor(m, off));
    if ((tid & 63) == 0) redm[tid >> 6] = m;
    __syncthreads();
    m = fmaxf(fmaxf(redm[0], redm[1]), fmaxf(redm[2], redm[3]));

    float ea = __expf(a - m), eb = __expf(b - m);
    float s = ea + eb;
#pragma unroll
    for (int off = 32; off > 0; off >>= 1) s += __shfl_xor(s, off);
    if ((tid & 63) == 0) reds[tid >> 6] = s;
    __syncthreads();
    s = reds[0] + reds[1] + reds[2] + reds[3];
    const float inv = 1.0f / s;

    const float fa = ea * inv, fb = eb * inv;
    const unsigned int packed = (unsigned int)f2bf(fa) | ((unsigned int)f2bf(fb) << 16);
    ((unsigned int*)(Pb + row * 512))[tid] = packed;

    if (*flag) {
        unsigned short* P = (unsigned short*)dout + 1048576;
        ((unsigned int*)(P + row * 512))[tid] = packed;
    } else {
        float* P = (float*)dout + 1048576;
        ((float2*)(P + row * 512))[tid] = make_float2(fa, fb);
    }
}

// ---------------------------------------------------------------------------
// out0[t][n][f] = (1/32)( sum_b x[t][b][n][f] + sum_{r<32} Y[n*32+r][t*128+f] )
// (buggy-reshape algebra folded in). One block per n, 8 e-cols per thread.
// ---------------------------------------------------------------------------
__global__ __launch_bounds__(256)
void final_reduce(const void* __restrict__ xv, const unsigned short* __restrict__ Y,
                  void* __restrict__ dout, const int* __restrict__ flag)
{
    const int n = blockIdx.x;
    const int tid = threadIdx.x;
    const int col0 = tid * 8;
    const int t = col0 >> 7, f0 = col0 & 127;
    const int isbf = *flag;

    float acc[8] = {0, 0, 0, 0, 0, 0, 0, 0};
    const unsigned short* yb = Y + (long)n * 32 * 2048 + col0;
    for (int rr = 0; rr < 32; rr++) {
        union { uint4 u; unsigned short s[8]; } U;
        U.u = *(const uint4*)(yb + (long)rr * 2048);
#pragma unroll
        for (int j = 0; j < 8; j++) acc[j] += bf2f(U.s[j]);
    }
    const long xoff = (long)t * 2097152 + n * 128 + f0;
    if (isbf) {
        const unsigned short* xb = (const unsigned short*)xv + xoff;
        for (int b = 0; b < 32; b++) {
            union { uint4 u; unsigned short s[8]; } U;
            U.u = *(const uint4*)(xb + (long)b * 65536);
#pragma unroll
            for (int j = 0; j < 8; j++) acc[j] += bf2f(U.s[j]);
        }
    } else {
        const float* xb = (const float*)xv + xoff;
        for (int b = 0; b < 32; b++) {
            float4 g0 = *(const float4*)(xb + (long)b * 65536);
            float4 g1 = *(const float4*)(xb + (long)b * 65536 + 4);
            acc[0] += g0.x; acc[1] += g0.y; acc[2] += g0.z; acc[3] += g0.w;
            acc[4] += g1.x; acc[5] += g1.y; acc[6] += g1.z; acc[7] += g1.w;
        }
    }
    const long oidx = (long)t * 65536 + n * 128 + f0;
    if (isbf) {
        union { uint4 u; unsigned short s[8]; } W;
#pragma unroll
        for (int j = 0; j < 8; j++) W.s[j] = f2bf(acc[j] * 0.03125f);
        *(uint4*)((unsigned short*)dout + oidx) = W.u;
    } else {
        float* o = (float*)dout + oidx;
#pragma unroll
        for (int j = 0; j < 8; j += 4) {
            float4 w = make_float4(acc[j] * 0.03125f, acc[j + 1] * 0.03125f,
                                   acc[j + 2] * 0.03125f, acc[j + 3] * 0.03125f);
            *(float4*)(o + j) = w;
        }
    }
}

// ---------------------------------------------------------------------------
extern "C" void kernel_launch(void* const* d_in, const int* in_sizes, int n_in,
                              void* d_out, int out_size, void* d_ws, size_t ws_size,
                              hipStream_t stream)
{
    // workspace map (u16 elements unless noted) -- 256MB + 16KB + 4B total:
    // R1: xr -> O        R2: Q -> Vt -> Y      R3: K -> Pb(16MB)
    unsigned short* R1 = (unsigned short*)d_ws;     // 64MB
    unsigned short* R2 = R1 + 33554432;             // 64MB
    unsigned short* R3 = R2 + 33554432;             // 64MB
    float*          S  = (float*)(R3 + 33554432);   // 32MB fp32
    unsigned short* Wqb  = (unsigned short*)(S + 8388608);  // 8MB each
    unsigned short* Wkb  = Wqb + 4194304;
    unsigned short* Wvb  = Wkb + 4194304;
    unsigned short* Wfcb = Wvb + 4194304;
    unsigned short* bqb  = Wfcb + 4194304;
    unsigned short* bkb  = bqb + 2048;
    unsigned short* bvb  = bkb + 2048;
    unsigned short* bfcb = bvb + 2048;
    int* flag = (int*)(bfcb + 2048);

    // 0. dtype detect (inspect Wq)
    detect_dtype<<<1, 64, 0, stream>>>((const unsigned short*)d_in[1], flag);
    // 1. canonicalize weights/biases to bf16
    convert_bf16<<<4096, 256, 0, stream>>>(d_in[1], Wqb,  4194304, flag);
    convert_bf16<<<4096, 256, 0, stream>>>(d_in[3], Wkb,  4194304, flag);
    convert_bf16<<<4096, 256, 0, stream>>>(d_in[5], Wvb,  4194304, flag);
    convert_bf16<<<4096, 256, 0, stream>>>(d_in[7], Wfcb, 4194304, flag);
    convert_bf16<<<2, 256, 0, stream>>>(d_in[2], bqb,  2048, flag);
    convert_bf16<<<2, 256, 0, stream>>>(d_in[4], bkb,  2048, flag);
    convert_bf16<<<2, 256, 0, stream>>>(d_in[6], bvb,  2048, flag);
    convert_bf16<<<2, 256, 0, stream>>>(d_in[8], bfcb, 2048, flag);
    // 2. permute x -> xr (R1)
    build_xr<<<16384, 256, 0, stream>>>(d_in[0], R1, flag);
    // 3. Q = xr*Wq^T + bq (R2) ; K = xr*Wk^T + bk (R3)
    gemm_nt<0, true><<<dim3(16, 128, 1), 256, 0, stream>>>(R1, Wqb, R2, bqb, 2048, 0, 0, 0, 2048);
    gemm_nt<0, true><<<dim3(16, 128, 1), 256, 0, stream>>>(R1, Wkb, R3, bkb, 2048, 0, 0, 0, 2048);
    // 4. S_b = Q_b * K_b^T (fp32)
    gemm_nt<1, false><<<dim3(4, 4, 32), 256, 0, stream>>>(R2, R3, S, nullptr, 2048, 1048576, 1048576, 262144, 512);
    // 5. P = softmax(S/sqrt(E)) -> Pb (R3, bf16) + attention chunk of d_out
    softmax_rows<<<16384, 256, 0, stream>>>(S, R3, d_out, flag);
    // 6. Vt[b][e][node] = (xr_b*Wv^T + bv)^T : A=Wv (M=2048), B=xr_b, bias-per-row -> R2
    gemm_nt<3, true><<<dim3(4, 16, 32), 256, 0, stream>>>(Wvb, R1, R2, bvb, 2048, 0, 1048576, 1048576, 512);
    // 7. O_b = P_b * Vt_b^T -> R1 (M=512, N=2048, K=512)
    gemm_nt<0, false><<<dim3(16, 4, 32), 256, 0, stream>>>(R3, R2, R1, nullptr, 512, 262144, 1048576, 1048576, 2048);
    // 8. Y = O * Wfc^T + bfc -> R2
    gemm_nt<0, true><<<dim3(16, 128, 1), 256, 0, stream>>>(R1, Wfcb, R2, bfcb, 2048, 0, 0, 0, 2048);
    // 9. out0 = x_mean + row-mean of Y
    final_reduce<<<512, 256, 0, stream>>>(d_in[0], R2, d_out, flag);
}

// Round 3
// 1021.906 us; speedup vs baseline: 1.1782x; 1.1782x over previous
//
#include <hip/hip_runtime.h>

typedef __attribute__((ext_vector_type(8))) __bf16 bf16x8;
typedef __attribute__((ext_vector_type(4))) float floatx4;

__device__ __forceinline__ float bf2f(unsigned short u) {
    union { unsigned int i; float f; } v; v.i = ((unsigned int)u) << 16; return v.f;
}
__device__ __forceinline__ unsigned short f2bf(float f) {
    union { float f; unsigned int i; } v; v.f = f;
    unsigned int u = v.i;
    return (unsigned short)((u + 0x7fffu + ((u >> 16) & 1u)) >> 16);
}

__device__ __forceinline__ void async16(const void* g, void* l) {
    __builtin_amdgcn_global_load_lds(
        (__attribute__((address_space(1))) void*)(g),
        (__attribute__((address_space(3))) void*)(l), 16, 0, 0);
}

// ---------------------------------------------------------------------------
// dtype detection on Wq (scale-0.02 values): bf16 -> exponent in [100,126];
// fp32 mantissa halves -> ~uniform. flag=1 -> bf16 inputs, 0 -> fp32.
// ---------------------------------------------------------------------------
__global__ void detect_dtype(const unsigned short* __restrict__ w, int* __restrict__ flag)
{
    int tid = threadIdx.x;  // 64
    int cnt = 0;
    for (int i = tid; i < 256; i += 64) {
        unsigned short s = w[2 * i];
        int e = (s >> 7) & 0xFF;
        if (e >= 100 && e <= 126) cnt++;
    }
#pragma unroll
    for (int off = 32; off > 0; off >>= 1) cnt += __shfl_xor(cnt, off);
    if (tid == 0) *flag = (cnt >= 128) ? 1 : 0;
}

__global__ __launch_bounds__(256)
void convert_bf16(const void* __restrict__ in, unsigned short* __restrict__ out,
                  int n, const int* __restrict__ flag)
{
    int i = (blockIdx.x * 256 + threadIdx.x) * 4;
    if (i >= n) return;
    if (*flag) {
        *(uint2*)(out + i) = *(const uint2*)((const unsigned short*)in + i);
    } else {
        float4 f = *(const float4*)((const float*)in + i);
        union { uint2 u; unsigned short s[4]; } W;
        W.s[0] = f2bf(f.x); W.s[1] = f2bf(f.y); W.s[2] = f2bf(f.z); W.s[3] = f2bf(f.w);
        *(uint2*)(out + i) = W.u;
    }
}

// ---------------------------------------------------------------------------
// xr[b*512+n][f*16+t] = x[t][b][n][f]
// ---------------------------------------------------------------------------
__global__ __launch_bounds__(256)
void build_xr(const void* __restrict__ xv, unsigned short* __restrict__ xr,
              const int* __restrict__ flag)
{
    __shared__ __align__(16) unsigned short tile[128 * 24];
    const int bn = blockIdx.x;
    const int b = bn >> 9, n = bn & 511;
    const int tid = threadIdx.x;
    const int t = tid >> 4, l16 = tid & 15;

    const long off = (long)(t * 32 + b) * 65536 + n * 128 + l16 * 8;
    union { uint4 u; unsigned short s[8]; } U;
    if (*flag) {
        U.u = *(const uint4*)((const unsigned short*)xv + off);
    } else {
        const float* xf = (const float*)xv + off;
        float4 f0 = *(const float4*)xf;
        float4 f1 = *(const float4*)(xf + 4);
        U.s[0] = f2bf(f0.x); U.s[1] = f2bf(f0.y); U.s[2] = f2bf(f0.z); U.s[3] = f2bf(f0.w);
        U.s[4] = f2bf(f1.x); U.s[5] = f2bf(f1.y); U.s[6] = f2bf(f1.z); U.s[7] = f2bf(f1.w);
    }
#pragma unroll
    for (int j = 0; j < 8; j++) tile[(l16 * 8 + j) * 24 + t] = U.s[j];
    __syncthreads();

    const int f = tid >> 1, t0 = (tid & 1) * 8;
    uint4 o = *(const uint4*)&tile[f * 24 + t0];
    *(uint4*)(xr + (long)bn * 2048 + tid * 8) = o;
}

// ---------------------------------------------------------------------------
// NT GEMM: C = A (MxK, lda) * B^T (B NxK, ldb), fp32 accum. 128x128 tile,
// BK=32, 4 waves x (4x4) 16x16x32 bf16 MFMA. MODE 0: bf16 + bias[col];
// MODE 1: fp32, no bias; MODE 3: bf16 + bias[row]. Batched via blockIdx.z.
// ---------------------------------------------------------------------------
template <int MODE, bool BIAS>
__global__ __launch_bounds__(256)
void gemm_nt(const unsigned short* __restrict__ Ag,
             const unsigned short* __restrict__ Bg,
             void* __restrict__ Cg,
             const unsigned short* __restrict__ bias,
             int K, long sA, long sB, long sC, int lda, int ldb, int ldc)
{
    __shared__ __align__(16) unsigned short lsA[128 * 32];
    __shared__ __align__(16) unsigned short lsB[128 * 32];

    const int tid = threadIdx.x;
    const int z = blockIdx.z;
    const unsigned short* A = Ag + (long)z * sA + (long)blockIdx.y * 128 * lda;
    const unsigned short* B = Bg + (long)z * sB + (long)blockIdx.x * 128 * ldb;

    const int wave = tid >> 6, lane = tid & 63;
    const int wm = (wave >> 1) * 64, wn = (wave & 1) * 64;
    const int r = lane & 15, quad = lane >> 4;

    floatx4 acc[4][4];
#pragma unroll
    for (int i = 0; i < 4; i++)
#pragma unroll
        for (int j = 0; j < 4; j++) acc[i][j] = floatx4{0.f, 0.f, 0.f, 0.f};

    const int srow = tid >> 2;
    const int scol = (tid & 3) * 8;
    const long a0 = (long)srow * lda + scol;
    const long a1 = (long)(srow + 64) * lda + scol;
    const long b0 = (long)srow * ldb + scol;
    const long b1 = (long)(srow + 64) * ldb + scol;

    for (int k0 = 0; k0 < K; k0 += 32) {
        async16(A + k0 + a0, (char*)lsA + tid * 16);
        async16(A + k0 + a1, (char*)lsA + 4096 + tid * 16);
        async16(B + k0 + b0, (char*)lsB + tid * 16);
        async16(B + k0 + b1, (char*)lsB + 4096 + tid * 16);
        __syncthreads();

        const bf16x8* pA = (const bf16x8*)lsA;
        const bf16x8* pB = (const bf16x8*)lsB;
        bf16x8 af[4], bb[4];
#pragma unroll
        for (int i = 0; i < 4; i++) af[i] = pA[(wm + i * 16 + r) * 4 + quad];
#pragma unroll
        for (int j = 0; j < 4; j++) bb[j] = pB[(wn + j * 16 + r) * 4 + quad];
#pragma unroll
        for (int i = 0; i < 4; i++)
#pragma unroll
            for (int j = 0; j < 4; j++)
                acc[i][j] = __builtin_amdgcn_mfma_f32_16x16x32_bf16(af[i], bb[j], acc[i][j], 0, 0, 0);
        __syncthreads();
    }

    // C/D layout: col = lane&15, row = quad*4 + reg
    const int mb = blockIdx.y * 128 + wm + quad * 4;
    const int nb = blockIdx.x * 128 + wn + r;

    if (MODE == 1) {
        float* C = (float*)Cg + (long)z * sC;
#pragma unroll
        for (int i = 0; i < 4; i++)
#pragma unroll
            for (int j = 0; j < 4; j++)
#pragma unroll
                for (int g = 0; g < 4; g++)
                    C[(long)(mb + i * 16 + g) * ldc + (nb + j * 16)] = acc[i][j][g];
    } else if (MODE == 0) {
        unsigned short* C = (unsigned short*)Cg + (long)z * sC;
#pragma unroll
        for (int j = 0; j < 4; j++) {
            const int n = nb + j * 16;
            const float bj = BIAS ? bf2f(bias[n]) : 0.0f;
#pragma unroll
            for (int i = 0; i < 4; i++)
#pragma unroll
                for (int g = 0; g < 4; g++)
                    C[(long)(mb + i * 16 + g) * ldc + n] = f2bf(acc[i][j][g] + bj);
        }
    } else { // MODE 3: bias per row
        unsigned short* C = (unsigned short*)Cg + (long)z * sC;
#pragma unroll
        for (int i = 0; i < 4; i++)
#pragma unroll
            for (int g = 0; g < 4; g++) {
                const int m = mb + i * 16 + g;
                const float bm = BIAS ? bf2f(bias[m]) : 0.0f;
#pragma unroll
                for (int j = 0; j < 4; j++)
                    C[(long)m * ldc + (nb + j * 16)] = f2bf(acc[i][j][g] + bm);
            }
    }
}

// ---------------------------------------------------------------------------
// Row softmax -> attention chunk of d_out only (dtype per flag).
// ---------------------------------------------------------------------------
__global__ __launch_bounds__(256)
void softmax_rows(const float* __restrict__ S, void* __restrict__ dout,
                  const int* __restrict__ flag)
{
    const long row = blockIdx.x;
    const int tid = threadIdx.x;
    const float scale = 0.02209708691207961f; // 1/sqrt(2048)
    float2 v = ((const float2*)(S + row * 512))[tid];
    float a = v.x * scale, b = v.y * scale;

    __shared__ float redm[4], reds[4];
    float m = fmaxf(a, b);
#pragma unroll
    for (int off = 32; off > 0; off >>= 1) m = fmaxf(m, __shfl_xor(m, off));
    if ((tid & 63) == 0) redm[tid >> 6] = m;
    __syncthreads();
    m = fmaxf(fmaxf(redm[0], redm[1]), fmaxf(redm[2], redm[3]));

    float ea = __expf(a - m), eb = __expf(b - m);
    float s = ea + eb;
#pragma unroll
    for (int off = 32; off > 0; off >>= 1) s += __shfl_xor(s, off);
    if ((tid & 63) == 0) reds[tid >> 6] = s;
    __syncthreads();
    s = reds[0] + reds[1] + reds[2] + reds[3];
    const float inv = 1.0f / s;
    const float fa = ea * inv, fb = eb * inv;

    if (*flag) {
        unsigned short* P = (unsigned short*)dout + 1048576;
        const unsigned int packed = (unsigned int)f2bf(fa) | ((unsigned int)f2bf(fb) << 16);
        ((unsigned int*)(P + row * 512))[tid] = packed;
    } else {
        float* P = (float*)dout + 1048576;
        ((float2*)(P + row * 512))[tid] = make_float2(fa, fb);
    }
}

// ---------------------------------------------------------------------------
// Pbar[g][l] = sum_{r<32} P[g*32+r][l]  (P read from d_out, dtype per flag)
// grid 512 blocks, 256 thr, 2 cols/thread. bf16 out.
// ---------------------------------------------------------------------------
__global__ __launch_bounds__(256)
void pbar_reduce(const void* __restrict__ dout, unsigned short* __restrict__ Pbar,
                 const int* __restrict__ flag)
{
    const int g = blockIdx.x, tid = threadIdx.x;
    float s0 = 0.f, s1 = 0.f;
    if (*flag) {
        const unsigned short* P = (const unsigned short*)dout + 1048576;
        const unsigned short* p = P + (long)g * 32 * 512 + tid * 2;
        for (int r = 0; r < 32; r++) {
            unsigned int u = *(const unsigned int*)(p + (long)r * 512);
            s0 += bf2f((unsigned short)(u & 0xffff));
            s1 += bf2f((unsigned short)(u >> 16));
        }
    } else {
        const float* P = (const float*)dout + 1048576;
        const float* p = P + (long)g * 32 * 512 + tid * 2;
        for (int r = 0; r < 32; r++) {
            float2 v = *(const float2*)(p + (long)r * 512);
            s0 += v.x; s1 += v.y;
        }
    }
    const unsigned int packed = (unsigned int)f2bf(s0) | ((unsigned int)f2bf(s1) << 16);
    ((unsigned int*)(Pbar + (long)g * 512))[tid] = packed;
}

// ---------------------------------------------------------------------------
// Obar[b*16+m][e] = sum_l Pbar[b*16+m][l] * Vt[b][e][l]
// One wave per 16x16 (m,e) tile, K=512 loop, fragments straight from global.
// grid (32 e-blocks of 64, 32 batches), 256 thr.
// ---------------------------------------------------------------------------
__global__ __launch_bounds__(256)
void pv_small(const unsigned short* __restrict__ Pbar,
              const unsigned short* __restrict__ Vt,
              unsigned short* __restrict__ Obar)
{
    const int b = blockIdx.y;
    const int wave = threadIdx.x >> 6, lane = threadIdx.x & 63;
    const int r = lane & 15, quad = lane >> 4;
    const int e0 = (blockIdx.x * 4 + wave) * 16;

    const unsigned short* Ab = Pbar + (long)b * 16 * 512;
    const unsigned short* Bb = Vt + (long)b * 1048576 + (long)e0 * 512;

    floatx4 acc = floatx4{0.f, 0.f, 0.f, 0.f};
    for (int k0 = 0; k0 < 512; k0 += 32) {
        bf16x8 a = *(const bf16x8*)(Ab + r * 512 + k0 + quad * 8);
        bf16x8 v = *(const bf16x8*)(Bb + r * 512 + k0 + quad * 8);
        acc = __builtin_amdgcn_mfma_f32_16x16x32_bf16(a, v, acc, 0, 0, 0);
    }
#pragma unroll
    for (int g = 0; g < 4; g++)
        Obar[(long)(b * 16 + quad * 4 + g) * 2048 + e0 + r] = f2bf(acc[g]);
}

// ---------------------------------------------------------------------------
// out0[t][n][f] = (1/32) sum_b x[t][b][n][f] + Ybar[n][t*128+f]/32 + bfc[..]
// ---------------------------------------------------------------------------
__global__ __launch_bounds__(256)
void final_small(const void* __restrict__ xv, const unsigned short* __restrict__ Ybar,
                 const unsigned short* __restrict__ bfcb, void* __restrict__ dout,
                 const int* __restrict__ flag)
{
    const int n = blockIdx.x;
    const int tid = threadIdx.x;
    const int col0 = tid * 8;
    const int t = col0 >> 7, f0 = col0 & 127;
    const int isbf = *flag;

    float acc[8];
    {
        union { uint4 u; unsigned short s[8]; } Yv, Bv;
        Yv.u = *(const uint4*)(Ybar + (long)n * 2048 + col0);
        Bv.u = *(const uint4*)(bfcb + col0);
#pragma unroll
        for (int j = 0; j < 8; j++) acc[j] = bf2f(Yv.s[j]) + 32.0f * bf2f(Bv.s[j]);
    }
    const long xoff = (long)t * 2097152 + n * 128 + f0;
    if (isbf) {
        const unsigned short* xb = (const unsigned short*)xv + xoff;
        for (int b = 0; b < 32; b++) {
            union { uint4 u; unsigned short s[8]; } U;
            U.u = *(const uint4*)(xb + (long)b * 65536);
#pragma unroll
            for (int j = 0; j < 8; j++) acc[j] += bf2f(U.s[j]);
        }
    } else {
        const float* xb = (const float*)xv + xoff;
        for (int b = 0; b < 32; b++) {
            float4 g0 = *(const float4*)(xb + (long)b * 65536);
            float4 g1 = *(const float4*)(xb + (long)b * 65536 + 4);
            acc[0] += g0.x; acc[1] += g0.y; acc[2] += g0.z; acc[3] += g0.w;
            acc[4] += g1.x; acc[5] += g1.y; acc[6] += g1.z; acc[7] += g1.w;
        }
    }
    const long oidx = (long)t * 65536 + n * 128 + f0;
    if (isbf) {
        union { uint4 u; unsigned short s[8]; } W;
#pragma unroll
        for (int j = 0; j < 8; j++) W.s[j] = f2bf(acc[j] * 0.03125f);
        *(uint4*)((unsigned short*)dout + oidx) = W.u;
    } else {
        float* o = (float*)dout + oidx;
#pragma unroll
        for (int j = 0; j < 8; j += 4)
            *(float4*)(o + j) = make_float4(acc[j] * 0.03125f, acc[j + 1] * 0.03125f,
                                            acc[j + 2] * 0.03125f, acc[j + 3] * 0.03125f);
    }
}

// ---------------------------------------------------------------------------
extern "C" void kernel_launch(void* const* d_in, const int* in_sizes, int n_in,
                              void* d_out, int out_size, void* d_ws, size_t ws_size,
                              hipStream_t stream)
{
    // ws map (u16 elems): R1 64MB (xr -> Pbar/Obar/Ybar), R23 128MB (QK -> Vt),
    // S 32MB fp32, weights 32MB, biases+flag. Total ~256.03MB.
    unsigned short* R1  = (unsigned short*)d_ws;       // 64MB
    unsigned short* R23 = R1 + 33554432;               // 128MB
    float*          S   = (float*)(R23 + 67108864);    // 32MB fp32
    unsigned short* Wqb  = (unsigned short*)(S + 8388608);
    unsigned short* Wkb  = Wqb + 4194304;              // adjacent to Wqb (fused QK)
    unsigned short* Wvb  = Wkb + 4194304;
    unsigned short* Wfcb = Wvb + 4194304;
    unsigned short* bqb  = Wfcb + 4194304;
    unsigned short* bkb  = bqb + 2048;                 // adjacent to bqb
    unsigned short* bvb  = bkb + 2048;
    unsigned short* bfcb = bvb + 2048;
    int* flag = (int*)(bfcb + 2048);

    unsigned short* xr   = R1;
    unsigned short* QK   = R23;                        // [16384][4096], Q=cols 0..2047, K=2048..4095
    unsigned short* Vt   = R23;                        // [32][2048][512] after QK dead
    unsigned short* Pbar = R1;                         // [512][512]   after xr dead
    unsigned short* Obar = Pbar + 262144;              // [512][2048]
    unsigned short* Ybar = Obar + 1048576;             // [512][2048]

    detect_dtype<<<1, 64, 0, stream>>>((const unsigned short*)d_in[1], flag);
    convert_bf16<<<4096, 256, 0, stream>>>(d_in[1], Wqb,  4194304, flag);
    convert_bf16<<<4096, 256, 0, stream>>>(d_in[3], Wkb,  4194304, flag);
    convert_bf16<<<4096, 256, 0, stream>>>(d_in[5], Wvb,  4194304, flag);
    convert_bf16<<<4096, 256, 0, stream>>>(d_in[7], Wfcb, 4194304, flag);
    convert_bf16<<<2, 256, 0, stream>>>(d_in[2], bqb,  2048, flag);
    convert_bf16<<<2, 256, 0, stream>>>(d_in[4], bkb,  2048, flag);
    convert_bf16<<<2, 256, 0, stream>>>(d_in[6], bvb,  2048, flag);
    convert_bf16<<<2, 256, 0, stream>>>(d_in[8], bfcb, 2048, flag);

    // 1. permute x -> xr
    build_xr<<<16384, 256, 0, stream>>>(d_in[0], xr, flag);
    // 2. fused [Q|K] = xr * [Wq;Wk]^T + [bq;bk]   (M=16384, N=4096, K=2048)
    gemm_nt<0, true><<<dim3(32, 128, 1), 256, 0, stream>>>(
        xr, Wqb, QK, bqb, 2048, 0, 0, 0, 2048, 2048, 4096);
    // 3. S_b = Q_b * K_b^T (fp32), lda/ldb = 4096
    gemm_nt<1, false><<<dim3(4, 4, 32), 256, 0, stream>>>(
        QK, QK + 2048, S, nullptr, 2048, 2097152, 2097152, 262144, 4096, 4096, 512);
    // 4. Vt[b][e][node] = (xr_b*Wv^T + bv)^T  (QK dead; writes into R23)
    gemm_nt<3, true><<<dim3(4, 16, 32), 256, 0, stream>>>(
        Wvb, xr, Vt, bvb, 2048, 0, 1048576, 1048576, 2048, 2048, 512);
    // 5. P = softmax(S/sqrt(E)) -> attention chunk of d_out
    softmax_rows<<<16384, 256, 0, stream>>>(S, d_out, flag);
    // 6. Pbar[g] = sum of 32 consecutive P rows (xr dead; R1 reused)
    pbar_reduce<<<512, 256, 0, stream>>>(d_out, Pbar, flag);
    // 7. Obar = Pbar * Vt^T per batch (M=16/batch)
    pv_small<<<dim3(32, 32), 256, 0, stream>>>(Pbar, Vt, Obar);
    // 8. Ybar = Obar * Wfc^T (no bias; folded into final)
    gemm_nt<0, false><<<dim3(16, 4, 1), 256, 0, stream>>>(
        Obar, Wfcb, Ybar, nullptr, 2048, 0, 0, 0, 2048, 2048, 2048);
    // 9. out0 = x_mean + Ybar/32 + bfc
    final_small<<<512, 256, 0, stream>>>(d_in[0], Ybar, bfcb, d_out, flag);
}

// Round 4
// 786.349 us; speedup vs baseline: 1.5312x; 1.2996x over previous
//
#include <hip/hip_runtime.h>

typedef __attribute__((ext_vector_type(8))) __bf16 bf16x8;
typedef __attribute__((ext_vector_type(4))) float floatx4;

__device__ __forceinline__ float bf2f(unsigned short u) {
    union { unsigned int i; float f; } v; v.i = ((unsigned int)u) << 16; return v.f;
}
__device__ __forceinline__ unsigned short f2bf(float f) {
    union { float f; unsigned int i; } v; v.f = f;
    unsigned int u = v.i;
    return (unsigned short)((u + 0x7fffu + ((u >> 16) & 1u)) >> 16);
}

__device__ __forceinline__ void async16(const void* g, void* l) {
    __builtin_amdgcn_global_load_lds(
        (__attribute__((address_space(1))) void*)(g),
        (__attribute__((address_space(3))) void*)(l), 16, 0, 0);
}

// ---------------------------------------------------------------------------
// dtype detect on Wq: bf16 scale-0.02 values have exponent in [100,126];
// fp32 mantissa low-halves are ~uniform. flag=1 -> bf16 inputs.
// ---------------------------------------------------------------------------
__global__ void detect_dtype(const unsigned short* __restrict__ w, int* __restrict__ flag)
{
    int tid = threadIdx.x;  // 64
    int cnt = 0;
    for (int i = tid; i < 256; i += 64) {
        unsigned short s = w[2 * i];
        int e = (s >> 7) & 0xFF;
        if (e >= 100 && e <= 126) cnt++;
    }
#pragma unroll
    for (int off = 32; off > 0; off >>= 1) cnt += __shfl_xor(cnt, off);
    if (tid == 0) *flag = (cnt >= 128) ? 1 : 0;
}

// convert to bf16 with optional scale (used for 32*bv)
__global__ __launch_bounds__(256)
void convert_bf16(const void* __restrict__ in, unsigned short* __restrict__ out,
                  int n, float scale, const int* __restrict__ flag)
{
    int i = (blockIdx.x * 256 + threadIdx.x) * 4;
    if (i >= n) return;
    float f[4];
    if (*flag) {
        const unsigned short* p = (const unsigned short*)in + i;
#pragma unroll
        for (int j = 0; j < 4; j++) f[j] = bf2f(p[j]);
    } else {
        float4 v = *(const float4*)((const float*)in + i);
        f[0] = v.x; f[1] = v.y; f[2] = v.z; f[3] = v.w;
    }
    union { uint2 u; unsigned short s[4]; } W;
#pragma unroll
    for (int j = 0; j < 4; j++) W.s[j] = f2bf(f[j] * scale);
    *(uint2*)(out + i) = W.u;
}

// ---------------------------------------------------------------------------
// WT[i][d] = W[d][i], 2048x2048, convert to bf16. 64x64 LDS tiles.
// ---------------------------------------------------------------------------
__global__ __launch_bounds__(256)
void transpose_conv(const void* __restrict__ in, unsigned short* __restrict__ out,
                    const int* __restrict__ flag)
{
    __shared__ unsigned short tile[64 * 65];
    const int d0 = blockIdx.x * 64, i0 = blockIdx.y * 64;
    const int tid = threadIdx.x;
    const int r = tid >> 2, seg = tid & 3;

    const long base = (long)(d0 + r) * 2048 + i0 + seg * 16;
    unsigned short vals[16];
    if (*flag) {
        const unsigned short* p = (const unsigned short*)in + base;
        union { uint4 u; unsigned short s[8]; } a, b;
        a.u = *(const uint4*)p; b.u = *(const uint4*)(p + 8);
#pragma unroll
        for (int j = 0; j < 8; j++) { vals[j] = a.s[j]; vals[8 + j] = b.s[j]; }
    } else {
        const float* p = (const float*)in + base;
#pragma unroll
        for (int q = 0; q < 4; q++) {
            float4 v = *(const float4*)(p + q * 4);
            vals[q * 4 + 0] = f2bf(v.x); vals[q * 4 + 1] = f2bf(v.y);
            vals[q * 4 + 2] = f2bf(v.z); vals[q * 4 + 3] = f2bf(v.w);
        }
    }
#pragma unroll
    for (int j = 0; j < 16; j++) tile[r * 65 + seg * 16 + j] = vals[j];
    __syncthreads();

    union { uint4 u[2]; unsigned short s[16]; } W;
#pragma unroll
    for (int j = 0; j < 16; j++) W.s[j] = tile[(seg * 16 + j) * 65 + r];
    unsigned short* o = out + (long)(i0 + r) * 2048 + d0 + seg * 16;
    *(uint4*)o = W.u[0];
    *(uint4*)(o + 8) = W.u[1];
}

// ---------------------------------------------------------------------------
// xr[b*512+n][f*16+t] = x[t][b][n][f]
// ---------------------------------------------------------------------------
__global__ __launch_bounds__(256)
void build_xr(const void* __restrict__ xv, unsigned short* __restrict__ xr,
              const int* __restrict__ flag)
{
    __shared__ __align__(16) unsigned short tile[128 * 24];
    const int bn = blockIdx.x;
    const int b = bn >> 9, n = bn & 511;
    const int tid = threadIdx.x;
    const int t = tid >> 4, l16 = tid & 15;

    const long off = (long)(t * 32 + b) * 65536 + n * 128 + l16 * 8;
    union { uint4 u; unsigned short s[8]; } U;
    if (*flag) {
        U.u = *(const uint4*)((const unsigned short*)xv + off);
    } else {
        const float* xf = (const float*)xv + off;
        float4 f0 = *(const float4*)xf;
        float4 f1 = *(const float4*)(xf + 4);
        U.s[0] = f2bf(f0.x); U.s[1] = f2bf(f0.y); U.s[2] = f2bf(f0.z); U.s[3] = f2bf(f0.w);
        U.s[4] = f2bf(f1.x); U.s[5] = f2bf(f1.y); U.s[6] = f2bf(f1.z); U.s[7] = f2bf(f1.w);
    }
#pragma unroll
    for (int j = 0; j < 8; j++) tile[(l16 * 8 + j) * 24 + t] = U.s[j];
    __syncthreads();

    const int f = tid >> 1, t0 = (tid & 1) * 8;
    uint4 o = *(const uint4*)&tile[f * 24 + t0];
    *(uint4*)(xr + (long)bn * 2048 + tid * 8) = o;
}

// ---------------------------------------------------------------------------
// NT GEMM: C = A (MxK, lda) * B^T (B NxK, ldb), fp32 accum. 128x128 tile,
// BK=32, 4 waves x (4x4) 16x16x32 bf16 MFMA. MODE 0: bf16 + bias[col];
// MODE 1: fp32, no bias. Batched via blockIdx.z.
// ---------------------------------------------------------------------------
template <int MODE, bool BIAS>
__global__ __launch_bounds__(256)
void gemm_nt(const unsigned short* __restrict__ Ag,
             const unsigned short* __restrict__ Bg,
             void* __restrict__ Cg,
             const unsigned short* __restrict__ bias,
             int K, long sA, long sB, long sC, int lda, int ldb, int ldc)
{
    __shared__ __align__(16) unsigned short lsA[128 * 32];
    __shared__ __align__(16) unsigned short lsB[128 * 32];

    const int tid = threadIdx.x;
    const int z = blockIdx.z;
    const unsigned short* A = Ag + (long)z * sA + (long)blockIdx.y * 128 * lda;
    const unsigned short* B = Bg + (long)z * sB + (long)blockIdx.x * 128 * ldb;

    const int wave = tid >> 6, lane = tid & 63;
    const int wm = (wave >> 1) * 64, wn = (wave & 1) * 64;
    const int r = lane & 15, quad = lane >> 4;

    floatx4 acc[4][4];
#pragma unroll
    for (int i = 0; i < 4; i++)
#pragma unroll
        for (int j = 0; j < 4; j++) acc[i][j] = floatx4{0.f, 0.f, 0.f, 0.f};

    const int srow = tid >> 2;
    const int scol = (tid & 3) * 8;
    const long a0 = (long)srow * lda + scol;
    const long a1 = (long)(srow + 64) * lda + scol;
    const long b0 = (long)srow * ldb + scol;
    const long b1 = (long)(srow + 64) * ldb + scol;

    for (int k0 = 0; k0 < K; k0 += 32) {
        async16(A + k0 + a0, (char*)lsA + tid * 16);
        async16(A + k0 + a1, (char*)lsA + 4096 + tid * 16);
        async16(B + k0 + b0, (char*)lsB + tid * 16);
        async16(B + k0 + b1, (char*)lsB + 4096 + tid * 16);
        __syncthreads();

        const bf16x8* pA = (const bf16x8*)lsA;
        const bf16x8* pB = (const bf16x8*)lsB;
        bf16x8 af[4], bb[4];
#pragma unroll
        for (int i = 0; i < 4; i++) af[i] = pA[(wm + i * 16 + r) * 4 + quad];
#pragma unroll
        for (int j = 0; j < 4; j++) bb[j] = pB[(wn + j * 16 + r) * 4 + quad];
#pragma unroll
        for (int i = 0; i < 4; i++)
#pragma unroll
            for (int j = 0; j < 4; j++)
                acc[i][j] = __builtin_amdgcn_mfma_f32_16x16x32_bf16(af[i], bb[j], acc[i][j], 0, 0, 0);
        __syncthreads();
    }

    // C/D layout: col = lane&15, row = quad*4 + reg
    const int mb = blockIdx.y * 128 + wm + quad * 4;
    const int nb = blockIdx.x * 128 + wn + r;

    if (MODE == 1) {
        float* C = (float*)Cg + (long)z * sC;
#pragma unroll
        for (int i = 0; i < 4; i++)
#pragma unroll
            for (int j = 0; j < 4; j++)
#pragma unroll
                for (int g = 0; g < 4; g++)
                    C[(long)(mb + i * 16 + g) * ldc + (nb + j * 16)] = acc[i][j][g];
    } else {
        unsigned short* C = (unsigned short*)Cg + (long)z * sC;
#pragma unroll
        for (int j = 0; j < 4; j++) {
            const int n = nb + j * 16;
            const float bj = BIAS ? bf2f(bias[n]) : 0.0f;
#pragma unroll
            for (int i = 0; i < 4; i++)
#pragma unroll
                for (int g = 0; g < 4; g++)
                    C[(long)(mb + i * 16 + g) * ldc + n] = f2bf(acc[i][j][g] + bj);
        }
    }
}

// ---------------------------------------------------------------------------
// w2[i] = sum_d WkT[i][d] * bq[d]   (one block per i)
// ---------------------------------------------------------------------------
__global__ __launch_bounds__(256)
void w2_kernel(const unsigned short* __restrict__ WkT,
               const unsigned short* __restrict__ bqb, float* __restrict__ w2)
{
    const int i = blockIdx.x, tid = threadIdx.x;
    const unsigned short* row = WkT + (long)i * 2048 + tid * 8;
    const unsigned short* bv = bqb + tid * 8;
    union { uint4 u; unsigned short s[8]; } A, B;
    A.u = *(const uint4*)row; B.u = *(const uint4*)bv;
    float s = 0.f;
#pragma unroll
    for (int j = 0; j < 8; j++) s += bf2f(A.s[j]) * bf2f(B.s[j]);
#pragma unroll
    for (int off = 32; off > 0; off >>= 1) s += __shfl_xor(s, off);
    __shared__ float red[4];
    if ((tid & 63) == 0) red[tid >> 6] = s;
    __syncthreads();
    if (tid == 0) w2[i] = red[0] + red[1] + red[2] + red[3];
}

// ---------------------------------------------------------------------------
// c[row] = sum_i xr[row][i] * w2[i]   (one wave per row)
// ---------------------------------------------------------------------------
__global__ __launch_bounds__(256)
void c_kernel(const unsigned short* __restrict__ xr, const float* __restrict__ w2,
              float* __restrict__ c)
{
    const int row = blockIdx.x * 4 + (threadIdx.x >> 6);
    const int lane = threadIdx.x & 63;
    float s = 0.f;
#pragma unroll
    for (int ch = 0; ch < 4; ch++) {
        const int i0 = ch * 512 + lane * 8;
        union { uint4 u; unsigned short s[8]; } X;
        X.u = *(const uint4*)(xr + (long)row * 2048 + i0);
        float4 w0 = *(const float4*)(w2 + i0);
        float4 w1 = *(const float4*)(w2 + i0 + 4);
        s += bf2f(X.s[0]) * w0.x + bf2f(X.s[1]) * w0.y + bf2f(X.s[2]) * w0.z + bf2f(X.s[3]) * w0.w;
        s += bf2f(X.s[4]) * w1.x + bf2f(X.s[5]) * w1.y + bf2f(X.s[6]) * w1.z + bf2f(X.s[7]) * w1.w;
    }
#pragma unroll
    for (int off = 32; off > 0; off >>= 1) s += __shfl_xor(s, off);
    if (lane == 0) c[row] = s;
}

// ---------------------------------------------------------------------------
// Row softmax of (S[row][k] + c[b*512+k]) * scale -> attention chunk of d_out.
// ---------------------------------------------------------------------------
__global__ __launch_bounds__(256)
void softmax_rows(const float* __restrict__ S, const float* __restrict__ c,
                  void* __restrict__ dout, const int* __restrict__ flag)
{
    const long row = blockIdx.x;
    const int tid = threadIdx.x;
    const float scale = 0.02209708691207961f; // 1/sqrt(2048)
    float2 v = ((const float2*)(S + row * 512))[tid];
    float2 cv = ((const float2*)(c + (row >> 9) * 512))[tid];
    float a = (v.x + cv.x) * scale, b = (v.y + cv.y) * scale;

    __shared__ float redm[4], reds[4];
    float m = fmaxf(a, b);
#pragma unroll
    for (int off = 32; off > 0; off >>= 1) m = fmaxf(m, __shfl_xor(m, off));
    if ((tid & 63) == 0) redm[tid >> 6] = m;
    __syncthreads();
    m = fmaxf(fmaxf(redm[0], redm[1]), fmaxf(redm[2], redm[3]));

    float ea = __expf(a - m), eb = __expf(b - m);
    float s = ea + eb;
#pragma unroll
    for (int off = 32; off > 0; off >>= 1) s += __shfl_xor(s, off);
    if ((tid & 63) == 0) reds[tid >> 6] = s;
    __syncthreads();
    s = reds[0] + reds[1] + reds[2] + reds[3];
    const float inv = 1.0f / s;
    const float fa = ea * inv, fb = eb * inv;

    if (*flag) {
        unsigned short* P = (unsigned short*)dout + 1048576;
        const unsigned int packed = (unsigned int)f2bf(fa) | ((unsigned int)f2bf(fb) << 16);
        ((unsigned int*)(P + row * 512))[tid] = packed;
    } else {
        float* P = (float*)dout + 1048576;
        ((float2*)(P + row * 512))[tid] = make_float2(fa, fb);
    }
}

// ---------------------------------------------------------------------------
// Pbar[g][l] = sum_{r<32} P[g*32+r][l]
// ---------------------------------------------------------------------------
__global__ __launch_bounds__(256)
void pbar_reduce(const void* __restrict__ dout, unsigned short* __restrict__ Pbar,
                 const int* __restrict__ flag)
{
    const int g = blockIdx.x, tid = threadIdx.x;
    float s0 = 0.f, s1 = 0.f;
    if (*flag) {
        const unsigned short* P = (const unsigned short*)dout + 1048576;
        const unsigned short* p = P + (long)g * 32 * 512 + tid * 2;
        for (int r = 0; r < 32; r++) {
            unsigned int u = *(const unsigned int*)(p + (long)r * 512);
            s0 += bf2f((unsigned short)(u & 0xffff));
            s1 += bf2f((unsigned short)(u >> 16));
        }
    } else {
        const float* P = (const float*)dout + 1048576;
        const float* p = P + (long)g * 32 * 512 + tid * 2;
        for (int r = 0; r < 32; r++) {
            float2 v = *(const float2*)(p + (long)r * 512);
            s0 += v.x; s1 += v.y;
        }
    }
    const unsigned int packed = (unsigned int)f2bf(s0) | ((unsigned int)f2bf(s1) << 16);
    ((unsigned int*)(Pbar + (long)g * 512))[tid] = packed;
}

// ---------------------------------------------------------------------------
// Z[b*16+m][d] = sum_l Pbar[b*16+m][l] * xr[b*512+l][d]
// grid (32 d-blocks of 64, 32 batches). LDS-staged xr tile, strided B-frags.
// ---------------------------------------------------------------------------
__global__ __launch_bounds__(256)
void z_kernel(const unsigned short* __restrict__ Pbar,
              const unsigned short* __restrict__ xr,
              unsigned short* __restrict__ Z)
{
    __shared__ __align__(16) unsigned short tile[32 * 64];
    const int b = blockIdx.y, d0 = blockIdx.x * 64;
    const int tid = threadIdx.x;
    const int wave = tid >> 6, lane = tid & 63;
    const int r = lane & 15, quad = lane >> 4;
    const unsigned short* xrb = xr + (long)b * 512 * 2048;

    floatx4 acc = floatx4{0.f, 0.f, 0.f, 0.f};
    for (int l0 = 0; l0 < 512; l0 += 32) {
        async16(xrb + (long)(l0 + (tid >> 3)) * 2048 + d0 + (tid & 7) * 8,
                (char*)tile + tid * 16);
        __syncthreads();
        bf16x8 a = *(const bf16x8*)(Pbar + (long)(b * 16 + r) * 512 + l0 + quad * 8);
        union { bf16x8 v; unsigned short s[8]; } bb;
#pragma unroll
        for (int j = 0; j < 8; j++) bb.s[j] = tile[(quad * 8 + j) * 64 + wave * 16 + r];
        acc = __builtin_amdgcn_mfma_f32_16x16x32_bf16(a, bb.v, acc, 0, 0, 0);
        __syncthreads();
    }
#pragma unroll
    for (int g = 0; g < 4; g++)
        Z[(long)(b * 16 + quad * 4 + g) * 2048 + d0 + wave * 16 + r] = f2bf(acc[g]);
}

// ---------------------------------------------------------------------------
// out0[t][n][f] = (1/32) sum_b x[t][b][n][f] + (Ybar[n][t*128+f] + 32*bfc)/32
// ---------------------------------------------------------------------------
__global__ __launch_bounds__(256)
void final_small(const void* __restrict__ xv, const unsigned short* __restrict__ Ybar,
                 const unsigned short* __restrict__ bfcb, void* __restrict__ dout,
                 const int* __restrict__ flag)
{
    const int n = blockIdx.x;
    const int tid = threadIdx.x;
    const int col0 = tid * 8;
    const int t = col0 >> 7, f0 = col0 & 127;
    const int isbf = *flag;

    float acc[8];
    {
        union { uint4 u; unsigned short s[8]; } Yv, Bv;
        Yv.u = *(const uint4*)(Ybar + (long)n * 2048 + col0);
        Bv.u = *(const uint4*)(bfcb + col0);
#pragma unroll
        for (int j = 0; j < 8; j++) acc[j] = bf2f(Yv.s[j]) + 32.0f * bf2f(Bv.s[j]);
    }
    const long xoff = (long)t * 2097152 + n * 128 + f0;
    if (isbf) {
        const unsigned short* xb = (const unsigned short*)xv + xoff;
        for (int b = 0; b < 32; b++) {
            union { uint4 u; unsigned short s[8]; } U;
            U.u = *(const uint4*)(xb + (long)b * 65536);
#pragma unroll
            for (int j = 0; j < 8; j++) acc[j] += bf2f(U.s[j]);
        }
    } else {
        const float* xb = (const float*)xv + xoff;
        for (int b = 0; b < 32; b++) {
            float4 g0 = *(const float4*)(xb + (long)b * 65536);
            float4 g1 = *(const float4*)(xb + (long)b * 65536 + 4);
            acc[0] += g0.x; acc[1] += g0.y; acc[2] += g0.z; acc[3] += g0.w;
            acc[4] += g1.x; acc[5] += g1.y; acc[6] += g1.z; acc[7] += g1.w;
        }
    }
    const long oidx = (long)t * 65536 + n * 128 + f0;
    if (isbf) {
        union { uint4 u; unsigned short s[8]; } W;
#pragma unroll
        for (int j = 0; j < 8; j++) W.s[j] = f2bf(acc[j] * 0.03125f);
        *(uint4*)((unsigned short*)dout + oidx) = W.u;
    } else {
        float* o = (float*)dout + oidx;
#pragma unroll
        for (int j = 0; j < 8; j += 4)
            *(float4*)(o + j) = make_float4(acc[j] * 0.03125f, acc[j + 1] * 0.03125f,
                                            acc[j + 2] * 0.03125f, acc[j + 3] * 0.03125f);
    }
}

// ---------------------------------------------------------------------------
extern "C" void kernel_launch(void* const* d_in, const int* in_sizes, int n_in,
                              void* d_out, int out_size, void* d_ws, size_t ws_size,
                              hipStream_t stream)
{
    // ws map (u16 elems unless noted), ~207 MB total
    unsigned short* xr   = (unsigned short*)d_ws;          // 64MB
    unsigned short* H    = xr + 33554432;                  // 64MB
    float*          S    = (float*)(H + 33554432);         // 32MB fp32
    unsigned short* Gt   = (unsigned short*)(S + 8388608); // 8MB
    unsigned short* WqT  = Gt  + 4194304;                  // 8MB
    unsigned short* WkT  = WqT + 4194304;                  // 8MB
    unsigned short* Wvb  = WkT + 4194304;                  // 8MB
    unsigned short* Wfcb = Wvb + 4194304;                  // 8MB
    unsigned short* Pbar = Wfcb + 4194304;                 // 0.5MB [512][512]
    unsigned short* Z    = Pbar + 262144;                  // 2MB [512][2048]
    unsigned short* Obar = Z + 1048576;                    // 2MB
    unsigned short* Ybar = Obar + 1048576;                 // 2MB
    unsigned short* bqb  = Ybar + 1048576;
    unsigned short* bvb  = bqb + 2048;                     // holds 32*bv
    unsigned short* bfcb = bvb + 2048;
    float*          w2   = (float*)(bfcb + 2048);          // [2048] fp32
    float*          c    = w2 + 2048;                      // [16384] fp32
    int*            flag = (int*)(c + 16384);

    detect_dtype<<<1, 64, 0, stream>>>((const unsigned short*)d_in[1], flag);
    // weights: Wq,Wk transposed; Wv,Wfc straight; biases (bv pre-scaled x32; bk cancels)
    transpose_conv<<<dim3(32, 32), 256, 0, stream>>>(d_in[1], WqT, flag);
    transpose_conv<<<dim3(32, 32), 256, 0, stream>>>(d_in[3], WkT, flag);
    convert_bf16<<<4096, 256, 0, stream>>>(d_in[5], Wvb,  4194304, 1.0f, flag);
    convert_bf16<<<4096, 256, 0, stream>>>(d_in[7], Wfcb, 4194304, 1.0f, flag);
    convert_bf16<<<2, 256, 0, stream>>>(d_in[2], bqb,  2048, 1.0f,  flag);
    convert_bf16<<<2, 256, 0, stream>>>(d_in[6], bvb,  2048, 32.0f, flag);
    convert_bf16<<<2, 256, 0, stream>>>(d_in[8], bfcb, 2048, 1.0f,  flag);

    // 1. permute x -> xr
    build_xr<<<16384, 256, 0, stream>>>(d_in[0], xr, flag);
    // 2. Gt[j][i] = (Wk^T Wq)[j][i]  (17 GF)
    gemm_nt<0, false><<<dim3(16, 16, 1), 256, 0, stream>>>(
        WkT, WqT, Gt, nullptr, 2048, 0, 0, 0, 2048, 2048, 2048);
    // 3. H = xr * G  (H[q][j] = sum_i xr[q][i] Gt[j][i], 137 GF)
    gemm_nt<0, false><<<dim3(16, 128, 1), 256, 0, stream>>>(
        xr, Gt, H, nullptr, 2048, 0, 0, 0, 2048, 2048, 2048);
    // 4. bias-correction GEMVs: w2 = WkT*bq; c = xr*w2
    w2_kernel<<<2048, 256, 0, stream>>>(WkT, bqb, w2);
    c_kernel<<<4096, 256, 0, stream>>>(xr, w2, c);
    // 5. S_b = H_b * xr_b^T (fp32, 34 GF)
    gemm_nt<1, false><<<dim3(4, 4, 32), 256, 0, stream>>>(
        H, xr, S, nullptr, 2048, 1048576, 1048576, 262144, 2048, 2048, 512);
    // 6. P = softmax((S + c)/sqrt(E)) -> attention chunk of d_out
    softmax_rows<<<16384, 256, 0, stream>>>(S, c, d_out, flag);
    // 7. Pbar[g] = sum of 32 consecutive P rows
    pbar_reduce<<<512, 256, 0, stream>>>(d_out, Pbar, flag);
    // 8. Z = Pbar_b * xr_b  (1 GF)
    z_kernel<<<dim3(32, 32), 256, 0, stream>>>(Pbar, xr, Z);
    // 9. Obar = Z * Wv^T + 32*bv  (4.3 GF)
    gemm_nt<0, true><<<dim3(16, 4, 1), 256, 0, stream>>>(
        Z, Wvb, Obar, bvb, 2048, 0, 0, 0, 2048, 2048, 2048);
    // 10. Ybar = Obar * Wfc^T  (4.3 GF; bfc folded into final)
    gemm_nt<0, false><<<dim3(16, 4, 1), 256, 0, stream>>>(
        Obar, Wfcb, Ybar, nullptr, 2048, 0, 0, 0, 2048, 2048, 2048);
    // 11. out0 = x_mean + (Ybar + 32*bfc)/32
    final_small<<<512, 256, 0, stream>>>(d_in[0], Ybar, bfcb, d_out, flag);
}